// Round 3
// baseline (730.494 us; speedup 1.0000x reference)
//
#include <hip/hip_runtime.h>

constexpr int kNR = 40000;
constexpr int kNU = 30000;
constexpr int kNP = 30000;
constexpr int kN  = 100000;          // total nodes
constexpr int kE  = 1600000;         // edges
constexpr int kF  = 128;             // feature/hidden dim
constexpr int kC  = 40;              // classes
constexpr int kSB = 98;              // ceil(kN/1024) scan blocks

// ---------- bf16 helpers (storage-only; math in fp32) ----------
__device__ __forceinline__ float bf_to_f(unsigned short h) {
    union { unsigned int i; float f; } u; u.i = ((unsigned int)h) << 16; return u.f;
}
__device__ __forceinline__ unsigned short f_to_bf(float f) {
    union { unsigned int i; float f; } u; u.f = f;
    unsigned int r = u.i + 0x7FFFu + ((u.i >> 16) & 1u);   // round-nearest-even
    return (unsigned short)(r >> 16);
}
__device__ __forceinline__ float2 bf2_to_f2(unsigned int p) {
    union { unsigned int i; float f; } lo, hi;
    lo.i = (p & 0xFFFFu) << 16;
    hi.i = p & 0xFFFF0000u;
    return make_float2(lo.f, hi.f);
}
__device__ __forceinline__ unsigned int pack_bf2(float a, float b) {
    return (unsigned int)f_to_bf(a) | ((unsigned int)f_to_bf(b) << 16);
}
// dtype-flexible float load: isbf ? bf16[i] : f32[i]
__device__ __forceinline__ float ldf(const void* p, int i, int isbf) {
    return isbf ? bf_to_f(((const unsigned short*)p)[i]) : ((const float*)p)[i];
}
// dtype-flexible edge load: is64 ? low word of int64[i] : int32[i]
__device__ __forceinline__ int lde(const int* p, int i, int is64) {
    return is64 ? p[2 * i] : p[i];
}

// ---------- sniff dtypes -> flags[0]=isbf, flags[1]=is64 ----------
__global__ void gcn_sniff(const unsigned int* __restrict__ w1w,
                          const int* __restrict__ eiw, int* __restrict__ flags) {
    if (blockIdx.x != 0 || threadIdx.x != 0) return;
    int plaus = 0;
    for (int k = 0; k < 64; k++) {
        unsigned int ax = w1w[k] & 0x7FFFu;        // low half as |bf16|
        plaus += (ax == 0u) || (ax > 0x2000u && ax < 0x4000u);
    }
    flags[0] = (plaus >= 48) ? 1 : 0;              // bf16 floats?
    int nz = 0;
    for (int k = 0; k < 64; k++) nz |= eiw[2 * k + 1];
    flags[1] = (nz == 0) ? 1 : 0;                  // int64 edges?
}

// ---------- sentinel: fill d_out with 1.0 (diagnostic; overwritten by gather2) ----------
__global__ void gcn_sentinel(unsigned int* __restrict__ out, const int* __restrict__ flags) {
    int limit = flags[0] ? (kN * kC / 2) : (kN * kC);   // words
    int i = blockIdx.x * 256 + threadIdx.x;
    if (i < limit) out[i] = 0x3F803F80u;   // bf16: (1.0,1.0); f32: 1.00009
}

__global__ void gcn_zero_i32(int* __restrict__ p, int n) {
    int i = blockIdx.x * 256 + threadIdx.x;
    if (i < n) p[i] = 0;
}

// ---------- fused weights: fw rows 0..17 = W_s @ W1, rows 18..20 = b_s @ W1 ----------
__global__ void gcn_fuse(const void* __restrict__ Wr, const void* __restrict__ br,
                         const void* __restrict__ Wu, const void* __restrict__ bu,
                         const void* __restrict__ Wp, const void* __restrict__ bp,
                         const void* __restrict__ W1, float* __restrict__ fw,
                         const int* __restrict__ flags) {
    int isbf = flags[0];
    int j = threadIdx.x;                 // 0..127: output column of W1
    float accR[5] = {0,0,0,0,0};
    float accU[7] = {0,0,0,0,0,0,0};
    float accP[6] = {0,0,0,0,0,0};
    float aR = 0.f, aU = 0.f, aP = 0.f;
    for (int k = 0; k < kF; k++) {
        float w1 = ldf(W1, k*kF + j, isbf);
        #pragma unroll
        for (int i = 0; i < 5; i++) accR[i] += ldf(Wr, i*kF + k, isbf) * w1;
        #pragma unroll
        for (int i = 0; i < 7; i++) accU[i] += ldf(Wu, i*kF + k, isbf) * w1;
        #pragma unroll
        for (int i = 0; i < 6; i++) accP[i] += ldf(Wp, i*kF + k, isbf) * w1;
        aR += ldf(br, k, isbf) * w1;
        aU += ldf(bu, k, isbf) * w1;
        aP += ldf(bp, k, isbf) * w1;
    }
    #pragma unroll
    for (int i = 0; i < 5; i++) fw[(0  + i)*kF + j] = accR[i];
    #pragma unroll
    for (int i = 0; i < 7; i++) fw[(5  + i)*kF + j] = accU[i];
    #pragma unroll
    for (int i = 0; i < 6; i++) fw[(12 + i)*kF + j] = accP[i];
    fw[18*kF + j] = aR;  fw[19*kF + j] = aU;  fw[20*kF + j] = aP;
}

// ---------- xw[n][0:128] = proj(input_n) @ W1, stored bf16 packed x2 ----------
__global__ void __launch_bounds__(256) gcn_xw(const void* __restrict__ xr,
                                              const void* __restrict__ xu,
                                              const void* __restrict__ xp,
                                              const float* __restrict__ fw,
                                              unsigned int* __restrict__ xw,
                                              const int* __restrict__ flags) {
    int isbf = flags[0];
    int t = blockIdx.x * 256 + threadIdx.x;
    if (t >= kN * 64) return;
    int n = t >> 6, j = t & 63;
    int f0 = 2 * j;
    const float* Wf; const void* base; int roff, d; float a0, a1;
    if (n < kNR) {
        Wf = fw;          base = xr; roff = n * 5;               d = 5;
        a0 = fw[18*kF + f0]; a1 = fw[18*kF + f0 + 1];
    } else if (n < kNR + kNU) {
        Wf = fw + 5*kF;   base = xu; roff = (n - kNR) * 7;       d = 7;
        a0 = fw[19*kF + f0]; a1 = fw[19*kF + f0 + 1];
    } else {
        Wf = fw + 12*kF;  base = xp; roff = (n - kNR - kNU) * 6; d = 6;
        a0 = fw[20*kF + f0]; a1 = fw[20*kF + f0 + 1];
    }
    for (int i = 0; i < d; i++) {
        float x = ldf(base, roff + i, isbf);
        a0 += x * Wf[i*kF + f0];
        a1 += x * Wf[i*kF + f0 + 1];
    }
    xw[t] = pack_bf2(a0, a1);
}

// ---------- CSR build ----------
__global__ void gcn_hist(const int* __restrict__ ei, int* __restrict__ cnt,
                         const int* __restrict__ flags) {
    int is64 = flags[1];
    int e = blockIdx.x * 256 + threadIdx.x;
    if (e < kE) {
        unsigned int d = (unsigned int)lde(ei, kE + e, is64);
        if (d < (unsigned int)kN) atomicAdd(&cnt[d], 1);
    }
}

__global__ void gcn_scan1(const int* __restrict__ cnt, int* __restrict__ bsums) {
    __shared__ int lds[256];
    int t = threadIdx.x;
    int base = blockIdx.x * 1024 + t * 4;
    int s = 0;
    #pragma unroll
    for (int j = 0; j < 4; j++) { int i = base + j; s += (i < kN) ? cnt[i] : 0; }
    lds[t] = s; __syncthreads();
    for (int o = 128; o > 0; o >>= 1) {
        if (t < o) lds[t] += lds[t + o];
        __syncthreads();
    }
    if (t == 0) bsums[blockIdx.x] = lds[0];
}

__global__ void gcn_scan2(int* __restrict__ bsums, int* __restrict__ rp) {
    __shared__ int lds[128];
    int t = threadIdx.x;
    int v = (t < kSB) ? bsums[t] : 0;
    int incl = v; lds[t] = incl; __syncthreads();
    for (int o = 1; o < 128; o <<= 1) {
        int y = (t >= o) ? lds[t - o] : 0;
        __syncthreads();
        incl += y; lds[t] = incl;
        __syncthreads();
    }
    if (t < kSB) bsums[t] = incl - v;     // exclusive block offsets
    if (t == 127) rp[kN] = incl;          // total (== kE when all dst valid)
}

__global__ void gcn_scan3(const int* __restrict__ cnt, const int* __restrict__ bsums,
                          int* __restrict__ rp, int* __restrict__ cur) {
    __shared__ int lds[256];
    int t = threadIdx.x;
    int base = blockIdx.x * 1024 + t * 4;
    int v0 = (base + 0 < kN) ? cnt[base + 0] : 0;
    int v1 = (base + 1 < kN) ? cnt[base + 1] : 0;
    int v2 = (base + 2 < kN) ? cnt[base + 2] : 0;
    int v3 = (base + 3 < kN) ? cnt[base + 3] : 0;
    int s = v0 + v1 + v2 + v3;
    int incl = s; lds[t] = incl; __syncthreads();
    for (int o = 1; o < 256; o <<= 1) {
        int y = (t >= o) ? lds[t - o] : 0;
        __syncthreads();
        incl += y; lds[t] = incl;
        __syncthreads();
    }
    int excl = incl - s + bsums[blockIdx.x];
    if (base + 0 < kN) { rp[base + 0] = excl; cur[base + 0] = excl; }  excl += v0;
    if (base + 1 < kN) { rp[base + 1] = excl; cur[base + 1] = excl; }  excl += v1;
    if (base + 2 < kN) { rp[base + 2] = excl; cur[base + 2] = excl; }  excl += v2;
    if (base + 3 < kN) { rp[base + 3] = excl; cur[base + 3] = excl; }
}

__global__ void gcn_fill(const int* __restrict__ ei, int* __restrict__ cur,
                         int* __restrict__ col, const int* __restrict__ flags) {
    int is64 = flags[1];
    int e = blockIdx.x * 256 + threadIdx.x;
    if (e < kE) {
        unsigned int d = (unsigned int)lde(ei, kE + e, is64);
        if (d < (unsigned int)kN) {
            int p = atomicAdd(&cur[d], 1);
            unsigned int s = (unsigned int)lde(ei, e, is64);
            if ((unsigned int)p < (unsigned int)kE)
                col[p] = (s < (unsigned int)kN) ? (int)s : 0;
        }
    }
}

// ---------- layer-1 gather (+ReLU): one wave per dst node, 2 feats/lane ----------
__global__ void __launch_bounds__(256) GCN_2190433321521_kernel(
        const unsigned int* __restrict__ xw,
        const int* __restrict__ rp,
        const int* __restrict__ col,
        unsigned int* __restrict__ h) {
    int w = (blockIdx.x * 256 + threadIdx.x) >> 6;
    int lane = threadIdx.x & 63;
    if (w >= kN) return;
    int beg = rp[w], end = rp[w + 1];
    float ax = 0.f, ay = 0.f;
    int e = beg;
    for (; e + 1 < end; e += 2) {
        int s0 = col[e], s1 = col[e + 1];
        float2 f0 = bf2_to_f2(xw[s0 * 64 + lane]);
        float2 f1 = bf2_to_f2(xw[s1 * 64 + lane]);
        ax += f0.x + f1.x;  ay += f0.y + f1.y;
    }
    if (e < end) {
        float2 f = bf2_to_f2(xw[col[e] * 64 + lane]);
        ax += f.x; ay += f.y;
    }
    ax = fmaxf(ax, 0.f);  ay = fmaxf(ay, 0.f);
    h[w * 64 + lane] = pack_bf2(ax, ay);
}

// ---------- hw = h @ W2 (W2 fp32 in LDS; 2 classes/thread) ----------
__global__ void __launch_bounds__(256) gcn_hw(const unsigned int* __restrict__ h,
                                              const void* __restrict__ W2,
                                              unsigned int* __restrict__ hw,
                                              const int* __restrict__ flags) {
    int isbf = flags[0];
    __shared__ float w2[kF * kC]; // 20 KB
    for (int i = threadIdx.x; i < kF * kC; i += 256) w2[i] = ldf(W2, i, isbf);
    __syncthreads();
    int t = blockIdx.x * 256 + threadIdx.x;
    if (t >= kN * 20) return;
    int n = t / 20, c0 = (t % 20) * 2;
    const uint4* hr4 = (const uint4*)(h + n * 64);
    float a0 = 0.f, a1 = 0.f;
    #pragma unroll 4
    for (int q = 0; q < 16; q++) {
        uint4 u = hr4[q];
        int k = q * 8;
        float2 p0 = bf2_to_f2(u.x), p1 = bf2_to_f2(u.y);
        float2 p2 = bf2_to_f2(u.z), p3 = bf2_to_f2(u.w);
        a0 += p0.x * w2[(k+0)*kC + c0] + p0.y * w2[(k+1)*kC + c0]
            + p1.x * w2[(k+2)*kC + c0] + p1.y * w2[(k+3)*kC + c0]
            + p2.x * w2[(k+4)*kC + c0] + p2.y * w2[(k+5)*kC + c0]
            + p3.x * w2[(k+6)*kC + c0] + p3.y * w2[(k+7)*kC + c0];
        a1 += p0.x * w2[(k+0)*kC + c0+1] + p0.y * w2[(k+1)*kC + c0+1]
            + p1.x * w2[(k+2)*kC + c0+1] + p1.y * w2[(k+3)*kC + c0+1]
            + p2.x * w2[(k+4)*kC + c0+1] + p2.y * w2[(k+5)*kC + c0+1]
            + p3.x * w2[(k+6)*kC + c0+1] + p3.y * w2[(k+7)*kC + c0+1];
    }
    hw[t] = pack_bf2(a0, a1);
}

// ---------- layer-2 gather: lanes 0..19, 2 classes/lane; dual-dtype store ----------
__global__ void __launch_bounds__(256) gcn_gather2(const unsigned int* __restrict__ hw,
                                                   const int* __restrict__ rp,
                                                   const int* __restrict__ col,
                                                   unsigned int* __restrict__ out,
                                                   const int* __restrict__ flags) {
    int isbf = flags[0];
    int w = (blockIdx.x * 256 + threadIdx.x) >> 6;
    int lane = threadIdx.x & 63;
    if (w >= kN || lane >= 20) return;
    int beg = rp[w], end = rp[w + 1];
    float ax = 0.f, ay = 0.f;
    int e = beg;
    for (; e + 1 < end; e += 2) {
        float2 f0 = bf2_to_f2(hw[col[e]     * 20 + lane]);
        float2 f1 = bf2_to_f2(hw[col[e + 1] * 20 + lane]);
        ax += f0.x + f1.x;  ay += f0.y + f1.y;
    }
    if (e < end) {
        float2 f = bf2_to_f2(hw[col[e] * 20 + lane]);
        ax += f.x; ay += f.y;
    }
    if (isbf) {
        out[w * 20 + lane] = pack_bf2(ax, ay);
    } else {
        float* of = (float*)out;
        of[w * 40 + 2*lane]     = ax;
        of[w * 40 + 2*lane + 1] = ay;
    }
}

extern "C" void kernel_launch(void* const* d_in, const int* in_sizes, int n_in,
                              void* d_out, int out_size, void* d_ws, size_t ws_size,
                              hipStream_t stream) {
    const void* xr = d_in[0];
    const void* xu = d_in[1];
    const void* xp = d_in[2];
    const int*  ei = (const int*)d_in[3];
    const void* Wr = d_in[4];
    const void* br = d_in[5];
    const void* Wu = d_in[6];
    const void* bu = d_in[7];
    const void* Wp = d_in[8];
    const void* bp = d_in[9];
    const void* W1 = d_in[10];
    const void* W2 = d_in[11];
    (void)in_sizes; (void)n_in; (void)out_size; (void)ws_size;

    char* ws = (char*)d_ws;
    size_t off = 0;
    auto alloc = [&](size_t bytes) -> void* {
        void* p = (void*)(ws + off);
        off = (off + bytes + 255) & ~(size_t)255;
        return p;
    };
    int*          flags = (int*)       alloc(256);
    int*          rp    = (int*)       alloc((size_t)(kN + 1) * 4);
    int*          cnt   = (int*)       alloc((size_t)kN * 4);
    int*          cur   = (int*)       alloc((size_t)kN * 4);
    int*          bs    = (int*)       alloc(128 * 4);
    float*        fw    = (float*)     alloc(21 * kF * 4);
    int*          col   = (int*)       alloc((size_t)kE * 4);        // 6.4 MB
    unsigned int* hwb   = (unsigned int*)alloc((size_t)kN * 20 * 4); // 8 MB
    unsigned int* xw    = (unsigned int*)alloc((size_t)kN * 64 * 4); // 25.6 MB
    unsigned int* h     = (unsigned int*)alloc((size_t)kN * 64 * 4); // 25.6 MB

    gcn_sniff<<<1, 64, 0, stream>>>((const unsigned int*)W1, ei, flags);
    gcn_sentinel<<<(kN * kC + 255) / 256, 256, 0, stream>>>((unsigned int*)d_out, flags);
    gcn_zero_i32<<<(kN + 255) / 256, 256, 0, stream>>>(cnt, kN);
    gcn_fuse<<<1, 128, 0, stream>>>(Wr, br, Wu, bu, Wp, bp, W1, fw, flags);
    gcn_xw<<<(kN * 64 + 255) / 256, 256, 0, stream>>>(xr, xu, xp, fw, xw, flags);
    gcn_hist<<<(kE + 255) / 256, 256, 0, stream>>>(ei, cnt, flags);
    gcn_scan1<<<kSB, 256, 0, stream>>>(cnt, bs);
    gcn_scan2<<<1, 128, 0, stream>>>(bs, rp);
    gcn_scan3<<<kSB, 256, 0, stream>>>(cnt, bs, rp, cur);
    gcn_fill<<<(kE + 255) / 256, 256, 0, stream>>>(ei, cur, col, flags);
    GCN_2190433321521_kernel<<<(kN * 64 + 255) / 256, 256, 0, stream>>>(xw, rp, col, h);
    gcn_hw<<<(kN * 20 + 255) / 256, 256, 0, stream>>>(h, W2, hwb, flags);
    gcn_gather2<<<(kN * 64 + 255) / 256, 256, 0, stream>>>(hwb, rp, col, (unsigned int*)d_out, flags);
}

// Round 4
// 519.178 us; speedup vs baseline: 1.4070x; 1.4070x over previous
//
#include <hip/hip_runtime.h>

constexpr int kNR = 40000;
constexpr int kNU = 30000;
constexpr int kNP = 30000;
constexpr int kN  = 100000;          // total nodes
constexpr int kE  = 1600000;         // edges
constexpr int kF  = 128;             // feature/hidden dim
constexpr int kC  = 40;              // classes
constexpr int kSB = 98;              // ceil(kN/1024) scan blocks

// ---------- bf16 helpers (storage-only; math in fp32) ----------
__device__ __forceinline__ float bf_to_f(unsigned short h) {
    union { unsigned int i; float f; } u; u.i = ((unsigned int)h) << 16; return u.f;
}
__device__ __forceinline__ unsigned short f_to_bf(float f) {
    union { unsigned int i; float f; } u; u.f = f;
    unsigned int r = u.i + 0x7FFFu + ((u.i >> 16) & 1u);   // round-nearest-even
    return (unsigned short)(r >> 16);
}
__device__ __forceinline__ float2 bf2_to_f2(unsigned int p) {
    union { unsigned int i; float f; } lo, hi;
    lo.i = (p & 0xFFFFu) << 16;
    hi.i = p & 0xFFFF0000u;
    return make_float2(lo.f, hi.f);
}
__device__ __forceinline__ unsigned int pack_bf2(float a, float b) {
    return (unsigned int)f_to_bf(a) | ((unsigned int)f_to_bf(b) << 16);
}
__device__ __forceinline__ float ldf(const void* p, int i, int isbf) {
    return isbf ? bf_to_f(((const unsigned short*)p)[i]) : ((const float*)p)[i];
}
__device__ __forceinline__ int lde(const int* p, int i, int is64) {
    return is64 ? p[2 * i] : p[i];
}

// ---------- sniff dtypes -> flags[0]=isbf, flags[1]=is64 ----------
__global__ void gcn_sniff(const unsigned int* __restrict__ w1w,
                          const int* __restrict__ eiw, int* __restrict__ flags) {
    if (blockIdx.x != 0 || threadIdx.x != 0) return;
    int plaus = 0;
    for (int k = 0; k < 64; k++) {
        unsigned int ax = w1w[k] & 0x7FFFu;
        plaus += (ax == 0u) || (ax > 0x2000u && ax < 0x4000u);
    }
    flags[0] = (plaus >= 48) ? 1 : 0;
    int nz = 0;
    for (int k = 0; k < 64; k++) nz |= eiw[2 * k + 1];
    flags[1] = (nz == 0) ? 1 : 0;
}

__global__ void gcn_zero_i32(int* __restrict__ p, int n) {
    int i = blockIdx.x * 256 + threadIdx.x;
    if (i < n) p[i] = 0;
}

// ---------- fused weights via LDS staging (was: 170us serial; now ~8us) ----------
// fw rows 0..17 = W_s @ W1, rows 18..20 = b_s @ W1   (fp32)
__global__ void gcn_fuse(const void* __restrict__ Wr, const void* __restrict__ br,
                         const void* __restrict__ Wu, const void* __restrict__ bu,
                         const void* __restrict__ Wp, const void* __restrict__ bp,
                         const void* __restrict__ W1, float* __restrict__ fw,
                         const int* __restrict__ flags) {
    __shared__ float sw[21 * kF];    // 10.5 KB: rows 0-4 Wr, 5-11 Wu, 12-17 Wp, 18 br, 19 bu, 20 bp
    int isbf = flags[0];
    int t = threadIdx.x;             // 128 threads
    for (int i = t; i < 21 * kF; i += 128) {
        int r = i >> 7, c = i & 127;
        float v;
        if (r < 5)        v = ldf(Wr, r * kF + c, isbf);
        else if (r < 12)  v = ldf(Wu, (r - 5) * kF + c, isbf);
        else if (r < 18)  v = ldf(Wp, (r - 12) * kF + c, isbf);
        else if (r == 18) v = ldf(br, c, isbf);
        else if (r == 19) v = ldf(bu, c, isbf);
        else              v = ldf(bp, c, isbf);
        sw[i] = v;
    }
    __syncthreads();
    int j = t;                       // output column of W1
    float acc[21];
    #pragma unroll
    for (int r = 0; r < 21; r++) acc[r] = 0.f;
    for (int k = 0; k < kF; k++) {
        float w1 = ldf(W1, k * kF + j, isbf);    // coalesced across j
        #pragma unroll
        for (int r = 0; r < 21; r++) acc[r] += sw[r * kF + k] * w1;  // LDS broadcast
    }
    #pragma unroll
    for (int r = 0; r < 21; r++) fw[r * kF + j] = acc[r];
}

// ---------- xw[n][0:128] = proj(input_n) @ W1, stored bf16 packed x2 ----------
__global__ void __launch_bounds__(256) gcn_xw(const void* __restrict__ xr,
                                              const void* __restrict__ xu,
                                              const void* __restrict__ xp,
                                              const float* __restrict__ fw,
                                              unsigned int* __restrict__ xw,
                                              const int* __restrict__ flags) {
    int isbf = flags[0];
    int t = blockIdx.x * 256 + threadIdx.x;
    if (t >= kN * 64) return;
    int n = t >> 6, j = t & 63;
    int f0 = 2 * j;
    const float* Wf; const void* base; int roff, d; float a0, a1;
    if (n < kNR) {
        Wf = fw;          base = xr; roff = n * 5;               d = 5;
        a0 = fw[18*kF + f0]; a1 = fw[18*kF + f0 + 1];
    } else if (n < kNR + kNU) {
        Wf = fw + 5*kF;   base = xu; roff = (n - kNR) * 7;       d = 7;
        a0 = fw[19*kF + f0]; a1 = fw[19*kF + f0 + 1];
    } else {
        Wf = fw + 12*kF;  base = xp; roff = (n - kNR - kNU) * 6; d = 6;
        a0 = fw[20*kF + f0]; a1 = fw[20*kF + f0 + 1];
    }
    for (int i = 0; i < d; i++) {
        float x = ldf(base, roff + i, isbf);
        a0 += x * Wf[i*kF + f0];
        a1 += x * Wf[i*kF + f0 + 1];
    }
    xw[t] = pack_bf2(a0, a1);
}

// ---------- CSR build ----------
__global__ void gcn_hist(const int* __restrict__ ei, int* __restrict__ cnt,
                         const int* __restrict__ flags) {
    int is64 = flags[1];
    int e = blockIdx.x * 256 + threadIdx.x;
    if (e < kE) {
        unsigned int d = (unsigned int)lde(ei, kE + e, is64);
        if (d < (unsigned int)kN) atomicAdd(&cnt[d], 1);
    }
}

__global__ void gcn_scan1(const int* __restrict__ cnt, int* __restrict__ bsums) {
    __shared__ int lds[256];
    int t = threadIdx.x;
    int base = blockIdx.x * 1024 + t * 4;
    int s = 0;
    #pragma unroll
    for (int j = 0; j < 4; j++) { int i = base + j; s += (i < kN) ? cnt[i] : 0; }
    lds[t] = s; __syncthreads();
    for (int o = 128; o > 0; o >>= 1) {
        if (t < o) lds[t] += lds[t + o];
        __syncthreads();
    }
    if (t == 0) bsums[blockIdx.x] = lds[0];
}

__global__ void gcn_scan2(int* __restrict__ bsums, int* __restrict__ rp) {
    __shared__ int lds[128];
    int t = threadIdx.x;
    int v = (t < kSB) ? bsums[t] : 0;
    int incl = v; lds[t] = incl; __syncthreads();
    for (int o = 1; o < 128; o <<= 1) {
        int y = (t >= o) ? lds[t - o] : 0;
        __syncthreads();
        incl += y; lds[t] = incl;
        __syncthreads();
    }
    if (t < kSB) bsums[t] = incl - v;
    if (t == 127) rp[kN] = incl;
}

__global__ void gcn_scan3(const int* __restrict__ cnt, const int* __restrict__ bsums,
                          int* __restrict__ rp, int* __restrict__ cur) {
    __shared__ int lds[256];
    int t = threadIdx.x;
    int base = blockIdx.x * 1024 + t * 4;
    int v0 = (base + 0 < kN) ? cnt[base + 0] : 0;
    int v1 = (base + 1 < kN) ? cnt[base + 1] : 0;
    int v2 = (base + 2 < kN) ? cnt[base + 2] : 0;
    int v3 = (base + 3 < kN) ? cnt[base + 3] : 0;
    int s = v0 + v1 + v2 + v3;
    int incl = s; lds[t] = incl; __syncthreads();
    for (int o = 1; o < 256; o <<= 1) {
        int y = (t >= o) ? lds[t - o] : 0;
        __syncthreads();
        incl += y; lds[t] = incl;
        __syncthreads();
    }
    int excl = incl - s + bsums[blockIdx.x];
    if (base + 0 < kN) { rp[base + 0] = excl; cur[base + 0] = excl; }  excl += v0;
    if (base + 1 < kN) { rp[base + 1] = excl; cur[base + 1] = excl; }  excl += v1;
    if (base + 2 < kN) { rp[base + 2] = excl; cur[base + 2] = excl; }  excl += v2;
    if (base + 3 < kN) { rp[base + 3] = excl; cur[base + 3] = excl; }
}

__global__ void gcn_fill(const int* __restrict__ ei, int* __restrict__ cur,
                         int* __restrict__ col, const int* __restrict__ flags) {
    int is64 = flags[1];
    int e = blockIdx.x * 256 + threadIdx.x;
    if (e < kE) {
        unsigned int d = (unsigned int)lde(ei, kE + e, is64);
        if (d < (unsigned int)kN) {
            int p = atomicAdd(&cur[d], 1);
            unsigned int s = (unsigned int)lde(ei, e, is64);
            if ((unsigned int)p < (unsigned int)kE)
                col[p] = (s < (unsigned int)kN) ? (int)s : 0;
        }
    }
}

// ---------- FUSED layer-1 gather + ReLU + @W2: grid-strided, one wave per node ----------
// Eliminates the 51MB h round-trip and the separate gcn_hw dispatch.
__global__ void __launch_bounds__(256) GCN_2190433321521_kernel(
        const unsigned int* __restrict__ xw,
        const int* __restrict__ rp,
        const int* __restrict__ col,
        const void* __restrict__ W2,
        unsigned short* __restrict__ hw,
        const int* __restrict__ flags) {
    __shared__ float w2f[kF * kC];   // 20 KB fp32
    __shared__ float hrow[4][kF];    // 2 KB: per-wave h row
    int isbf = flags[0];
    for (int i = threadIdx.x; i < kF * kC; i += 256) w2f[i] = ldf(W2, i, isbf);
    __syncthreads();                 // once; no barriers inside the node loop
    int lane = threadIdx.x & 63;
    int wid  = threadIdx.x >> 6;
    float* hr = hrow[wid];
    int stride = gridDim.x * 4;
    for (int n = blockIdx.x * 4 + wid; n < kN; n += stride) {
        int beg = rp[n], end = rp[n + 1];
        float ax = 0.f, ay = 0.f;
        int e = beg;
        for (; e + 3 < end; e += 4) {        // 4 edges in flight (MLP)
            int s0 = col[e], s1 = col[e+1], s2 = col[e+2], s3 = col[e+3];
            float2 f0 = bf2_to_f2(xw[s0 * 64 + lane]);
            float2 f1 = bf2_to_f2(xw[s1 * 64 + lane]);
            float2 f2 = bf2_to_f2(xw[s2 * 64 + lane]);
            float2 f3 = bf2_to_f2(xw[s3 * 64 + lane]);
            ax += (f0.x + f1.x) + (f2.x + f3.x);
            ay += (f0.y + f1.y) + (f2.y + f3.y);
        }
        for (; e < end; e++) {
            float2 f = bf2_to_f2(xw[col[e] * 64 + lane]);
            ax += f.x; ay += f.y;
        }
        // h row to LDS (wave-synchronous: same-wave DS ops are ordered; no barrier)
        hr[2*lane]     = fmaxf(ax, 0.f);
        hr[2*lane + 1] = fmaxf(ay, 0.f);
        if (lane < kC) {                     // lanes 0..39: one class each
            float acc = 0.f;
            #pragma unroll 8
            for (int k = 0; k < kF; k++)
                acc += hr[k] * w2f[k * kC + lane];   // hr broadcast; w2f <=2-way
            hw[(size_t)n * kC + lane] = f_to_bf(acc);
        }
    }
}

// ---------- layer-2 gather: 3 edge-groups x 20 class-lanes per wave ----------
__global__ void __launch_bounds__(256) gcn_gather2(const unsigned int* __restrict__ hw32,
                                                   const int* __restrict__ rp,
                                                   const int* __restrict__ col,
                                                   unsigned int* __restrict__ out,
                                                   const int* __restrict__ flags) {
    int isbf = flags[0];
    int w = (blockIdx.x * 256 + threadIdx.x) >> 6;
    if (w >= kN) return;
    int lane = threadIdx.x & 63;
    int grp = lane / 20;          // 0..2 active, 3 idle
    int c2  = lane % 20;          // class pair
    int beg = rp[w], end = rp[w + 1];
    float ax = 0.f, ay = 0.f;
    if (grp < 3) {
        for (int e = beg + grp; e < end; e += 3) {
            float2 f = bf2_to_f2(hw32[col[e] * 20 + c2]);
            ax += f.x; ay += f.y;
        }
    }
    // reduce the 3 groups onto lanes 0..19
    ax += __shfl(ax, lane + 20, 64) + __shfl(ax, lane + 40, 64);
    ay += __shfl(ay, lane + 20, 64) + __shfl(ay, lane + 40, 64);
    if (lane < 20) {
        if (isbf) {
            out[w * 20 + lane] = pack_bf2(ax, ay);
        } else {
            float* of = (float*)out;
            of[w * 40 + 2*lane]     = ax;
            of[w * 40 + 2*lane + 1] = ay;
        }
    }
}

extern "C" void kernel_launch(void* const* d_in, const int* in_sizes, int n_in,
                              void* d_out, int out_size, void* d_ws, size_t ws_size,
                              hipStream_t stream) {
    const void* xr = d_in[0];
    const void* xu = d_in[1];
    const void* xp = d_in[2];
    const int*  ei = (const int*)d_in[3];
    const void* Wr = d_in[4];
    const void* br = d_in[5];
    const void* Wu = d_in[6];
    const void* bu = d_in[7];
    const void* Wp = d_in[8];
    const void* bp = d_in[9];
    const void* W1 = d_in[10];
    const void* W2 = d_in[11];
    (void)in_sizes; (void)n_in; (void)out_size; (void)ws_size;

    char* ws = (char*)d_ws;
    size_t off = 0;
    auto alloc = [&](size_t bytes) -> void* {
        void* p = (void*)(ws + off);
        off = (off + bytes + 255) & ~(size_t)255;
        return p;
    };
    int*            flags = (int*)           alloc(256);
    int*            rp    = (int*)           alloc((size_t)(kN + 1) * 4);
    int*            cnt   = (int*)           alloc((size_t)kN * 4);
    int*            cur   = (int*)           alloc((size_t)kN * 4);
    int*            bs    = (int*)           alloc(128 * 4);
    float*          fw    = (float*)         alloc(21 * kF * 4);
    int*            col   = (int*)           alloc((size_t)kE * 4);       // 6.4 MB
    unsigned short* hwb   = (unsigned short*)alloc((size_t)kN * kC * 2);  // 8 MB bf16
    unsigned int*   xw    = (unsigned int*)  alloc((size_t)kN * 64 * 4);  // 25.6 MB

    gcn_sniff<<<1, 64, 0, stream>>>((const unsigned int*)W1, ei, flags);
    gcn_zero_i32<<<(kN + 255) / 256, 256, 0, stream>>>(cnt, kN);
    gcn_fuse<<<1, 128, 0, stream>>>(Wr, br, Wu, bu, Wp, bp, W1, fw, flags);
    gcn_xw<<<(kN * 64 + 255) / 256, 256, 0, stream>>>(xr, xu, xp, fw, xw, flags);
    gcn_hist<<<(kE + 255) / 256, 256, 0, stream>>>(ei, cnt, flags);
    gcn_scan1<<<kSB, 256, 0, stream>>>(cnt, bs);
    gcn_scan2<<<1, 128, 0, stream>>>(bs, rp);
    gcn_scan3<<<kSB, 256, 0, stream>>>(cnt, bs, rp, cur);
    gcn_fill<<<(kE + 255) / 256, 256, 0, stream>>>(ei, cur, col, flags);
    // 1792 blocks = 7 blocks/CU (22.5KB LDS) * 256 CU, grid-strided over nodes
    GCN_2190433321521_kernel<<<1792, 256, 0, stream>>>(xw, rp, col, W2, hwb, flags);
    gcn_gather2<<<(kN * 64 + 255) / 256, 256, 0, stream>>>((const unsigned int*)hwb, rp, col,
                                                           (unsigned int*)d_out, flags);
}

// Round 5
// 469.248 us; speedup vs baseline: 1.5567x; 1.1064x over previous
//
#include <hip/hip_runtime.h>

constexpr int kNR = 40000;
constexpr int kNU = 30000;
constexpr int kNP = 30000;
constexpr int kN  = 100000;          // total nodes
constexpr int kE  = 1600000;         // edges
constexpr int kF  = 128;             // feature/hidden dim
constexpr int kC  = 40;              // classes
constexpr int kSB = 98;              // ceil(kN/1024) scan blocks

// ---------- bf16 helpers (storage-only; math in fp32) ----------
__device__ __forceinline__ float bf_to_f(unsigned short h) {
    union { unsigned int i; float f; } u; u.i = ((unsigned int)h) << 16; return u.f;
}
__device__ __forceinline__ unsigned short f_to_bf(float f) {
    union { unsigned int i; float f; } u; u.f = f;
    unsigned int r = u.i + 0x7FFFu + ((u.i >> 16) & 1u);   // round-nearest-even
    return (unsigned short)(r >> 16);
}
__device__ __forceinline__ float2 bf2_to_f2(unsigned int p) {
    union { unsigned int i; float f; } lo, hi;
    lo.i = (p & 0xFFFFu) << 16;
    hi.i = p & 0xFFFF0000u;
    return make_float2(lo.f, hi.f);
}
__device__ __forceinline__ unsigned int pack_bf2(float a, float b) {
    return (unsigned int)f_to_bf(a) | ((unsigned int)f_to_bf(b) << 16);
}
__device__ __forceinline__ float ldf(const void* p, int i, int isbf) {
    return isbf ? bf_to_f(((const unsigned short*)p)[i]) : ((const float*)p)[i];
}
__device__ __forceinline__ int lde(const int* p, int i, int is64) {
    return is64 ? p[2 * i] : p[i];
}

// ---------- sniff dtypes -> flags[0]=isbf, flags[1]=is64 ----------
__global__ void gcn_sniff(const unsigned int* __restrict__ w1w,
                          const int* __restrict__ eiw, int* __restrict__ flags) {
    if (blockIdx.x != 0 || threadIdx.x != 0) return;
    int plaus = 0;
    for (int k = 0; k < 64; k++) {
        unsigned int ax = w1w[k] & 0x7FFFu;
        plaus += (ax == 0u) || (ax > 0x2000u && ax < 0x4000u);
    }
    flags[0] = (plaus >= 48) ? 1 : 0;
    int nz = 0;
    for (int k = 0; k < 64; k++) nz |= eiw[2 * k + 1];
    flags[1] = (nz == 0) ? 1 : 0;
}

__global__ void gcn_zero_i32(int* __restrict__ p, int n) {
    int i = blockIdx.x * 256 + threadIdx.x;
    if (i < n) p[i] = 0;
}

// ---------- fused weights via LDS staging ----------
// fw rows 0..17 = W_s @ W1, rows 18..20 = b_s @ W1   (fp32)
__global__ void gcn_fuse(const void* __restrict__ Wr, const void* __restrict__ br,
                         const void* __restrict__ Wu, const void* __restrict__ bu,
                         const void* __restrict__ Wp, const void* __restrict__ bp,
                         const void* __restrict__ W1, float* __restrict__ fw,
                         const int* __restrict__ flags) {
    __shared__ float sw[21 * kF];    // rows 0-4 Wr, 5-11 Wu, 12-17 Wp, 18 br, 19 bu, 20 bp
    int isbf = flags[0];
    int t = threadIdx.x;             // 128 threads
    for (int i = t; i < 21 * kF; i += 128) {
        int r = i >> 7, c = i & 127;
        float v;
        if (r < 5)        v = ldf(Wr, r * kF + c, isbf);
        else if (r < 12)  v = ldf(Wu, (r - 5) * kF + c, isbf);
        else if (r < 18)  v = ldf(Wp, (r - 12) * kF + c, isbf);
        else if (r == 18) v = ldf(br, c, isbf);
        else if (r == 19) v = ldf(bu, c, isbf);
        else              v = ldf(bp, c, isbf);
        sw[i] = v;
    }
    __syncthreads();
    int j = t;                       // output column of W1
    float acc[21];
    #pragma unroll
    for (int r = 0; r < 21; r++) acc[r] = 0.f;
    for (int k = 0; k < kF; k++) {
        float w1 = ldf(W1, k * kF + j, isbf);    // coalesced across j
        #pragma unroll
        for (int r = 0; r < 21; r++) acc[r] += sw[r * kF + k] * w1;  // LDS broadcast
    }
    #pragma unroll
    for (int r = 0; r < 21; r++) fw[r * kF + j] = acc[r];
}

// ---------- xw[n][0:128] = proj(input_n) @ W1, stored bf16 packed x2 ----------
__global__ void __launch_bounds__(256) gcn_xw(const void* __restrict__ xr,
                                              const void* __restrict__ xu,
                                              const void* __restrict__ xp,
                                              const float* __restrict__ fw,
                                              unsigned int* __restrict__ xw,
                                              const int* __restrict__ flags) {
    int isbf = flags[0];
    int t = blockIdx.x * 256 + threadIdx.x;
    if (t >= kN * 64) return;
    int n = t >> 6, j = t & 63;
    int f0 = 2 * j;
    const float* Wf; const void* base; int roff, d; float a0, a1;
    if (n < kNR) {
        Wf = fw;          base = xr; roff = n * 5;               d = 5;
        a0 = fw[18*kF + f0]; a1 = fw[18*kF + f0 + 1];
    } else if (n < kNR + kNU) {
        Wf = fw + 5*kF;   base = xu; roff = (n - kNR) * 7;       d = 7;
        a0 = fw[19*kF + f0]; a1 = fw[19*kF + f0 + 1];
    } else {
        Wf = fw + 12*kF;  base = xp; roff = (n - kNR - kNU) * 6; d = 6;
        a0 = fw[20*kF + f0]; a1 = fw[20*kF + f0 + 1];
    }
    for (int i = 0; i < d; i++) {
        float x = ldf(base, roff + i, isbf);
        a0 += x * Wf[i*kF + f0];
        a1 += x * Wf[i*kF + f0 + 1];
    }
    xw[t] = pack_bf2(a0, a1);
}

// ---------- CSR build ----------
__global__ void gcn_hist(const int* __restrict__ ei, int* __restrict__ cnt,
                         const int* __restrict__ flags) {
    int is64 = flags[1];
    int e = blockIdx.x * 256 + threadIdx.x;
    if (e < kE) {
        unsigned int d = (unsigned int)lde(ei, kE + e, is64);
        if (d < (unsigned int)kN) atomicAdd(&cnt[d], 1);
    }
}

__global__ void gcn_scan1(const int* __restrict__ cnt, int* __restrict__ bsums) {
    __shared__ int lds[256];
    int t = threadIdx.x;
    int base = blockIdx.x * 1024 + t * 4;
    int s = 0;
    #pragma unroll
    for (int j = 0; j < 4; j++) { int i = base + j; s += (i < kN) ? cnt[i] : 0; }
    lds[t] = s; __syncthreads();
    for (int o = 128; o > 0; o >>= 1) {
        if (t < o) lds[t] += lds[t + o];
        __syncthreads();
    }
    if (t == 0) bsums[blockIdx.x] = lds[0];
}

__global__ void gcn_scan2(int* __restrict__ bsums, int* __restrict__ rp) {
    __shared__ int lds[128];
    int t = threadIdx.x;
    int v = (t < kSB) ? bsums[t] : 0;
    int incl = v; lds[t] = incl; __syncthreads();
    for (int o = 1; o < 128; o <<= 1) {
        int y = (t >= o) ? lds[t - o] : 0;
        __syncthreads();
        incl += y; lds[t] = incl;
        __syncthreads();
    }
    if (t < kSB) bsums[t] = incl - v;
    if (t == 127) rp[kN] = incl;
}

__global__ void gcn_scan3(const int* __restrict__ cnt, const int* __restrict__ bsums,
                          int* __restrict__ rp, int* __restrict__ cur) {
    __shared__ int lds[256];
    int t = threadIdx.x;
    int base = blockIdx.x * 1024 + t * 4;
    int v0 = (base + 0 < kN) ? cnt[base + 0] : 0;
    int v1 = (base + 1 < kN) ? cnt[base + 1] : 0;
    int v2 = (base + 2 < kN) ? cnt[base + 2] : 0;
    int v3 = (base + 3 < kN) ? cnt[base + 3] : 0;
    int s = v0 + v1 + v2 + v3;
    int incl = s; lds[t] = incl; __syncthreads();
    for (int o = 1; o < 256; o <<= 1) {
        int y = (t >= o) ? lds[t - o] : 0;
        __syncthreads();
        incl += y; lds[t] = incl;
        __syncthreads();
    }
    int excl = incl - s + bsums[blockIdx.x];
    if (base + 0 < kN) { rp[base + 0] = excl; cur[base + 0] = excl; }  excl += v0;
    if (base + 1 < kN) { rp[base + 1] = excl; cur[base + 1] = excl; }  excl += v1;
    if (base + 2 < kN) { rp[base + 2] = excl; cur[base + 2] = excl; }  excl += v2;
    if (base + 3 < kN) { rp[base + 3] = excl; cur[base + 3] = excl; }
}

// ---------- fill, XCD-localized: blockIdx%8 owns dst range [r*12500, (r+1)*12500) ----------
// All writers of a given col window share one XCD (round-robin dispatch heuristic), so
// partial lines merge in that XCD's L2 and evict ONCE full, instead of 1.6M masked
// 64B fabric writes (R4: WRITE_SIZE=105MB, 130us). Correct for ANY block->XCD mapping.
__global__ void __launch_bounds__(256) gcn_fill(const int* __restrict__ ei,
                                                int* __restrict__ cur,
                                                int* __restrict__ col,
                                                const int* __restrict__ flags) {
    int is64 = flags[1];
    int r  = blockIdx.x & 7;                 // XCD slot (heuristic)
    int vb = blockIdx.x >> 3;                // virtual block within group: 0..255
    int lo = r * (kN / 8);                   // 12500-node range per group
    int hi = lo + (kN / 8);
    const int gthreads = 256 * 256;          // threads per group
    for (int e = vb * 256 + (int)threadIdx.x; e < kE; e += gthreads) {
        int d = lde(ei, kE + e, is64);
        if (d >= lo && d < hi) {
            int p = atomicAdd(&cur[d], 1);
            unsigned int s = (unsigned int)lde(ei, e, is64);
            if ((unsigned int)p < (unsigned int)kE)
                col[p] = (s < (unsigned int)kN) ? (int)s : 0;
        }
    }
}

// ---------- FUSED layer-1 gather + ReLU + @W2: grid-strided, one wave per node ----------
__global__ void __launch_bounds__(256) GCN_2190433321521_kernel(
        const unsigned int* __restrict__ xw,
        const int* __restrict__ rp,
        const int* __restrict__ col,
        const void* __restrict__ W2,
        unsigned short* __restrict__ hw,
        const int* __restrict__ flags) {
    __shared__ float w2f[kF * kC];   // 20 KB fp32
    __shared__ float hrow[4][kF];    // 2 KB: per-wave h row
    int isbf = flags[0];
    for (int i = threadIdx.x; i < kF * kC; i += 256) w2f[i] = ldf(W2, i, isbf);
    __syncthreads();                 // once; no barriers inside the node loop
    int lane = threadIdx.x & 63;
    int wid  = threadIdx.x >> 6;
    float* hr = hrow[wid];
    int stride = gridDim.x * 4;
    for (int n = blockIdx.x * 4 + wid; n < kN; n += stride) {
        int beg = rp[n], end = rp[n + 1];
        float ax = 0.f, ay = 0.f;
        int e = beg;
        for (; e + 3 < end; e += 4) {        // 4 edges in flight (MLP)
            int s0 = col[e], s1 = col[e+1], s2 = col[e+2], s3 = col[e+3];
            float2 f0 = bf2_to_f2(xw[s0 * 64 + lane]);
            float2 f1 = bf2_to_f2(xw[s1 * 64 + lane]);
            float2 f2 = bf2_to_f2(xw[s2 * 64 + lane]);
            float2 f3 = bf2_to_f2(xw[s3 * 64 + lane]);
            ax += (f0.x + f1.x) + (f2.x + f3.x);
            ay += (f0.y + f1.y) + (f2.y + f3.y);
        }
        for (; e < end; e++) {
            float2 f = bf2_to_f2(xw[col[e] * 64 + lane]);
            ax += f.x; ay += f.y;
        }
        // h row to LDS (same-wave DS ops are ordered; no barrier needed)
        hr[2*lane]     = fmaxf(ax, 0.f);
        hr[2*lane + 1] = fmaxf(ay, 0.f);
        if (lane < kC) {                     // lanes 0..39: one class each
            float acc = 0.f;
            #pragma unroll 8
            for (int k = 0; k < kF; k++)
                acc += hr[k] * w2f[k * kC + lane];
            hw[(size_t)n * kC + lane] = f_to_bf(acc);
        }
    }
}

// ---------- layer-2 gather: 3 edge-groups x 20 class-lanes per wave ----------
__global__ void __launch_bounds__(256) gcn_gather2(const unsigned int* __restrict__ hw32,
                                                   const int* __restrict__ rp,
                                                   const int* __restrict__ col,
                                                   unsigned int* __restrict__ out,
                                                   const int* __restrict__ flags) {
    int isbf = flags[0];
    int w = (blockIdx.x * 256 + threadIdx.x) >> 6;
    if (w >= kN) return;
    int lane = threadIdx.x & 63;
    int grp = lane / 20;          // 0..2 active, 3 idle
    int c2  = lane % 20;          // class pair
    int beg = rp[w], end = rp[w + 1];
    float ax = 0.f, ay = 0.f;
    if (grp < 3) {
        for (int e = beg + grp; e < end; e += 3) {
            float2 f = bf2_to_f2(hw32[col[e] * 20 + c2]);
            ax += f.x; ay += f.y;
        }
    }
    ax += __shfl(ax, lane + 20, 64) + __shfl(ax, lane + 40, 64);
    ay += __shfl(ay, lane + 20, 64) + __shfl(ay, lane + 40, 64);
    if (lane < 20) {
        if (isbf) {
            out[w * 20 + lane] = pack_bf2(ax, ay);
        } else {
            float* of = (float*)out;
            of[w * 40 + 2*lane]     = ax;
            of[w * 40 + 2*lane + 1] = ay;
        }
    }
}

extern "C" void kernel_launch(void* const* d_in, const int* in_sizes, int n_in,
                              void* d_out, int out_size, void* d_ws, size_t ws_size,
                              hipStream_t stream) {
    const void* xr = d_in[0];
    const void* xu = d_in[1];
    const void* xp = d_in[2];
    const int*  ei = (const int*)d_in[3];
    const void* Wr = d_in[4];
    const void* br = d_in[5];
    const void* Wu = d_in[6];
    const void* bu = d_in[7];
    const void* Wp = d_in[8];
    const void* bp = d_in[9];
    const void* W1 = d_in[10];
    const void* W2 = d_in[11];
    (void)in_sizes; (void)n_in; (void)out_size; (void)ws_size;

    char* ws = (char*)d_ws;
    size_t off = 0;
    auto alloc = [&](size_t bytes) -> void* {
        void* p = (void*)(ws + off);
        off = (off + bytes + 255) & ~(size_t)255;
        return p;
    };
    int*            flags = (int*)           alloc(256);
    int*            rp    = (int*)           alloc((size_t)(kN + 1) * 4);
    int*            cnt   = (int*)           alloc((size_t)kN * 4);
    int*            cur   = (int*)           alloc((size_t)kN * 4);
    int*            bs    = (int*)           alloc(128 * 4);
    float*          fw    = (float*)         alloc(21 * kF * 4);
    int*            col   = (int*)           alloc((size_t)kE * 4);       // 6.4 MB
    unsigned short* hwb   = (unsigned short*)alloc((size_t)kN * kC * 2);  // 8 MB bf16
    unsigned int*   xw    = (unsigned int*)  alloc((size_t)kN * 64 * 4);  // 25.6 MB

    gcn_sniff<<<1, 64, 0, stream>>>((const unsigned int*)W1, ei, flags);
    gcn_zero_i32<<<(kN + 255) / 256, 256, 0, stream>>>(cnt, kN);
    gcn_fuse<<<1, 128, 0, stream>>>(Wr, br, Wu, bu, Wp, bp, W1, fw, flags);
    gcn_xw<<<(kN * 64 + 255) / 256, 256, 0, stream>>>(xr, xu, xp, fw, xw, flags);
    gcn_hist<<<(kE + 255) / 256, 256, 0, stream>>>(ei, cnt, flags);
    gcn_scan1<<<kSB, 256, 0, stream>>>(cnt, bs);
    gcn_scan2<<<1, 128, 0, stream>>>(bs, rp);
    gcn_scan3<<<kSB, 256, 0, stream>>>(cnt, bs, rp, cur);
    gcn_fill<<<2048, 256, 0, stream>>>(ei, cur, col, flags);   // 8 XCD-local dst ranges
    GCN_2190433321521_kernel<<<1792, 256, 0, stream>>>(xw, rp, col, W2, hwb, flags);
    gcn_gather2<<<(kN * 64 + 255) / 256, 256, 0, stream>>>((const unsigned int*)hwb, rp, col,
                                                           (unsigned int*)d_out, flags);
}